// Round 3
// baseline (92.546 us; speedup 1.0000x reference)
//
#include <hip/hip_runtime.h>
#include <math.h>

namespace {
constexpr int kB = 512;
constexpr int kNDist = 511;   // bonds / lengths
constexpr int kNAng = 510;
constexpr int kNDih = 509;
constexpr float kPi = 3.14159265358979323846f;
}

__device__ __forceinline__ float shflu(float v, int off) {
  return __shfl_up(v, off, 64);
}

// K1: lengths[j] = mean over batch of distances[:, j].
// Single block, no atomics, no scratch init. Thread t owns column t;
// row-major loads are coalesced across the 511 active lanes.
__global__ __launch_bounds__(512) void k_lengths(const float* __restrict__ dist,
                                                 float* __restrict__ len) {
  const int t = threadIdx.x;
  if (t >= kNDist) return;
  float acc = 0.f;
#pragma unroll 8
  for (int r = 0; r < kB; ++r) {
    acc += dist[(size_t)r * kNDist + t];
  }
  len[t] = acc * (1.0f / 512.0f);
}

// K2: one block (512 thr) per batch. Wave-shuffle scans, 5 barriers total.
__global__ __launch_bounds__(512) void k_backmap(
    const float* __restrict__ angles,
    const float* __restrict__ dih,
    const float* __restrict__ len,
    float* __restrict__ out) {
  const int b = blockIdx.x;
  const int tid = threadIdx.x;
  const int wave = tid >> 6;     // 0..7
  const int lane = tid & 63;

  __shared__ float s_cx[512];
  __shared__ float s_cy[512];
  __shared__ float s_ws1[8];      // theta wave sums
  __shared__ float s_ws2[8][2];   // xy wave sums
  __shared__ float s_wq[2][4][4]; // quat wave totals
  __shared__ float s_wv[2][4][3]; // vec wave totals

  // ---------- Phase A: theta scan over 510 angle terms ----------
  float t0 = 0.f;
  if (tid < kNAng) {
    const float sa = (tid & 1) ? -1.f : 1.f;
    t0 = sa * (kPi - angles[(size_t)b * kNAng + tid]);
  }
  float iv = t0;
#pragma unroll
  for (int off = 1; off < 64; off <<= 1) {
    float w = shflu(iv, off);
    if (lane >= off) iv += w;
  }
  if (lane == 63) s_ws1[wave] = iv;
  __syncthreads();  // (1)
  float p = 0.f;
  for (int j = 0; j < wave; ++j) p += s_ws1[j];
  float full = iv + p;
  float prevScan = shflu(full, 1);
  if (lane == 0) prevScan = p;

  float theta = 0.f;
  if (tid >= 1 && tid < kNDist) {
    const float sa = ((tid - 1) & 1) ? -1.f : 1.f;
    theta = sa * prevScan;
  }

  // ---------- Phase A2: dx/dy scan -> planar cart ----------
  float dxv = 0.f, dyv = 0.f;
  if (tid < kNDist) {
    float sn, cs;
    sincosf(theta, &sn, &cs);
    const float L = len[tid];
    const float sg = (tid & 1) ? -1.f : 1.f;
    dxv = L * cs;
    dyv = L * sn * sg;
  }
  float ix = dxv, iy = dyv;
#pragma unroll
  for (int off = 1; off < 64; off <<= 1) {
    float wx = shflu(ix, off);
    float wy = shflu(iy, off);
    if (lane >= off) { ix += wx; iy += wy; }
  }
  if (lane == 63) { s_ws2[wave][0] = ix; s_ws2[wave][1] = iy; }
  __syncthreads();  // (2)
  float px = 0.f, py = 0.f;
  for (int j = 0; j < wave; ++j) { px += s_ws2[j][0]; py += s_ws2[j][1]; }
  float fx = ix + px, fy = iy + py;
  float cxe = shflu(fx, 1), cye = shflu(fy, 1);
  if (lane == 0) { cxe = px; cye = py; }
  s_cx[tid] = cxe;
  s_cy[tid] = cye;
  __syncthreads();  // (3)

  // ---------- Phase B: per-side quaternion prefix product ----------
  // left (side 0): bonds b_k = cart[255-k]-cart[256-k], k=0..255; phi_k = dih[254-k]+pi, k<255
  // right (side 1): bonds b_k = cart[257+k]-cart[256+k], k=0..254; phi_k = dih[255+k]+pi, k<254
  const int side = tid >> 8;
  const int k = tid & 255;
  const int swave = (tid >> 6) & 3;
  const int nb = side ? 255 : 256;
  const int ng = side ? 254 : 255;

  float bx = 0.f, by = 0.f;
  if (k < nb) {
    const int i0 = side ? (256 + k) : (256 - k);
    const int i1 = side ? (257 + k) : (255 - k);
    bx = s_cx[i1] - s_cx[i0];
    by = s_cy[i1] - s_cy[i0];
  }

  // G_k as quaternion (identity when k >= ng)
  float qw = 1.f, qx = 0.f, qy = 0.f, qz = 0.f;
  if (k < ng) {
    const float phi = side ? (dih[(size_t)b * kNDih + 255 + k] + kPi)
                           : (dih[(size_t)b * kNDih + 254 - k] + kPi);
    const float rn = rsqrtf(bx * bx + by * by);
    float sh, ch;
    sincosf(0.5f * phi, &sh, &ch);
    qw = ch;
    qx = sh * bx * rn;
    qy = sh * by * rn;
    // qz = 0 (planar axis)
  }
  // intra-wave non-commutative inclusive scan: q_l <- q_{l-off} (x) q_l
#pragma unroll
  for (int off = 1; off < 64; off <<= 1) {
    float aw = shflu(qw, off), ax = shflu(qx, off),
          ay = shflu(qy, off), az = shflu(qz, off);
    if (lane >= off) {
      const float nw = aw * qw - ax * qx - ay * qy - az * qz;
      const float nx = aw * qx + ax * qw + ay * qz - az * qy;
      const float ny = aw * qy - ax * qz + ay * qw + az * qx;
      const float nz = aw * qz + ax * qy - ay * qx + az * qw;
      qw = nw; qx = nx; qy = ny; qz = nz;
    }
  }
  if (lane == 63) {
    float* W = s_wq[side][swave];
    W[0] = qw; W[1] = qx; W[2] = qy; W[3] = qz;
  }
  __syncthreads();  // (4)
  // wave prefix P = product of earlier wave totals (in order)
  float Pw = 1.f, Px = 0.f, Py = 0.f, Pz = 0.f;
  for (int j = 0; j < swave; ++j) {
    const float* W = s_wq[side][j];
    const float aw = Pw, ax = Px, ay = Py, az = Pz;
    const float bw = W[0], bxq = W[1], byq = W[2], bzq = W[3];
    Pw = aw * bw - ax * bxq - ay * byq - az * bzq;
    Px = aw * bxq + ax * bw + ay * bzq - az * byq;
    Py = aw * byq - ax * bzq + ay * bw + az * bxq;
    Pz = aw * bzq + ax * byq - ay * bxq + az * bw;
  }
  // full inclusive Q = P (x) q
  float Qw = Pw * qw - Px * qx - Py * qy - Pz * qz;
  float Qx = Pw * qx + Px * qw + Py * qz - Pz * qy;
  float Qy = Pw * qy - Px * qz + Py * qw + Pz * qx;
  float Qz = Pw * qz + Px * qy - Py * qx + Pz * qw;
  // exclusive W_k = Q_{k-1}
  float Ww = shflu(Qw, 1), Wx = shflu(Qx, 1), Wy = shflu(Qy, 1), Wz = shflu(Qz, 1);
  if (lane == 0) { Ww = Pw; Wx = Px; Wy = Py; Wz = Pz; }

  // rotate bond (bx,by,0) by quaternion W: c = b + Ww*t + Wv x t, t = 2 Wv x b
  const float tx = -2.f * Wz * by;
  const float ty = 2.f * Wz * bx;
  const float tz = 2.f * (Wx * by - Wy * bx);
  float cx = bx + Ww * tx + (Wy * tz - Wz * ty);
  float cy = by + Ww * ty + (Wz * tx - Wx * tz);
  float cz = Ww * tz + (Wx * ty - Wy * tx);

  // ---------- Phase B2: float3 inclusive scan of rotated bonds ----------
  float vx = cx, vy = cy, vz = cz;
#pragma unroll
  for (int off = 1; off < 64; off <<= 1) {
    float ax = shflu(vx, off), ay = shflu(vy, off), az = shflu(vz, off);
    if (lane >= off) { vx += ax; vy += ay; vz += az; }
  }
  if (lane == 63) {
    float* V = s_wv[side][swave];
    V[0] = vx; V[1] = vy; V[2] = vz;
  }
  __syncthreads();  // (5)
  float sx = 0.f, sy = 0.f, sz = 0.f;
  for (int j = 0; j < swave; ++j) {
    const float* V = s_wv[side][j];
    sx += V[0]; sy += V[1]; sz += V[2];
  }
  vx += sx; vy += sy; vz += sz;

  // ---------- output assembly: flip(new_l) ++ new_r[3:] ----------
  const float bpx = s_cx[256], bpy = s_cy[256];
  const float ox = bpx + vx, oy = bpy + vy, oz = vz;
  float* outb = out + (size_t)b * 512 * 3;
  if (side == 0) {
    const int row = 255 - k;
    outb[row * 3 + 0] = ox; outb[row * 3 + 1] = oy; outb[row * 3 + 2] = oz;
  } else {
    if (k >= 1 && k <= 254) {
      const int row = 257 + k;
      outb[row * 3 + 0] = ox; outb[row * 3 + 1] = oy; outb[row * 3 + 2] = oz;
    }
    if (k == 0) {
      outb[256 * 3 + 0] = bpx; outb[256 * 3 + 1] = bpy; outb[256 * 3 + 2] = 0.f;
    }
    if (k == 255) {
      outb[257 * 3 + 0] = s_cx[257]; outb[257 * 3 + 1] = s_cy[257];
      outb[257 * 3 + 2] = 0.f;
    }
  }
}

extern "C" void kernel_launch(void* const* d_in, const int* in_sizes, int n_in,
                              void* d_out, int out_size, void* d_ws, size_t ws_size,
                              hipStream_t stream) {
  const float* distances = (const float*)d_in[0];
  const float* angles    = (const float*)d_in[1];
  const float* dihedrals = (const float*)d_in[2];
  float* lengths = (float*)d_ws;  // 511 floats of scratch, written then read
  float* out = (float*)d_out;
  k_lengths<<<1, 512, 0, stream>>>(distances, lengths);
  k_backmap<<<kB, 512, 0, stream>>>(angles, dihedrals, lengths, out);
}

// Round 5
// 71.138 us; speedup vs baseline: 1.3009x; 1.3009x over previous
//
#include <hip/hip_runtime.h>
#include <math.h>

namespace {
constexpr int kB = 512;
constexpr int kNDist = 511;   // bonds / lengths
constexpr int kNAng = 510;
constexpr int kNDih = 509;
constexpr float kPi = 3.14159265358979323846f;
}

__device__ __forceinline__ float shflu(float v, int off) {
  return __shfl_up(v, off, 64);
}

// K1: lengths[j] = mean over batch of distances[:, j].
// One block per column j; 256 threads stride the 512 rows.
// (Best-measured variant: grid-parallel, no atomics, no scratch init,
//  off the critical path in ~3 µs across 511 blocks.)
__global__ __launch_bounds__(256) void k_lengths(const float* __restrict__ dist,
                                                 float* __restrict__ len) {
  __shared__ float red[256];
  const int j = blockIdx.x;
  const int t = threadIdx.x;
  float s = dist[(size_t)t * kNDist + j] + dist[(size_t)(t + 256) * kNDist + j];
  red[t] = s;
  __syncthreads();
#pragma unroll
  for (int off = 128; off > 0; off >>= 1) {
    if (t < off) red[t] += red[t + off];
    __syncthreads();
  }
  if (t == 0) len[j] = red[0] * (1.0f / 512.0f);
}

// K2: one block (512 thr) per batch. Wave-shuffle scans, 5 barriers total.
__global__ __launch_bounds__(512) void k_backmap(
    const float* __restrict__ angles,
    const float* __restrict__ dih,
    const float* __restrict__ len,
    float* __restrict__ out) {
  const int b = blockIdx.x;
  const int tid = threadIdx.x;
  const int wave = tid >> 6;     // 0..7
  const int lane = tid & 63;

  __shared__ float s_cx[512];
  __shared__ float s_cy[512];
  __shared__ float s_ws1[8];      // theta wave sums
  __shared__ float s_ws2[8][2];   // xy wave sums
  __shared__ float s_wq[2][4][4]; // quat wave totals
  __shared__ float s_wv[2][4][3]; // vec wave totals

  // ---------- Phase A: theta scan over 510 angle terms ----------
  float t0 = 0.f;
  if (tid < kNAng) {
    const float sa = (tid & 1) ? -1.f : 1.f;
    t0 = sa * (kPi - angles[(size_t)b * kNAng + tid]);
  }
  float iv = t0;
#pragma unroll
  for (int off = 1; off < 64; off <<= 1) {
    float w = shflu(iv, off);
    if (lane >= off) iv += w;
  }
  if (lane == 63) s_ws1[wave] = iv;
  __syncthreads();  // (1)
  float p = 0.f;
  for (int j = 0; j < wave; ++j) p += s_ws1[j];
  float full = iv + p;
  float prevScan = shflu(full, 1);
  if (lane == 0) prevScan = p;

  float theta = 0.f;
  if (tid >= 1 && tid < kNDist) {
    const float sa = ((tid - 1) & 1) ? -1.f : 1.f;
    theta = sa * prevScan;
  }

  // ---------- Phase A2: dx/dy scan -> planar cart ----------
  float dxv = 0.f, dyv = 0.f;
  if (tid < kNDist) {
    float sn, cs;
    sincosf(theta, &sn, &cs);
    const float L = len[tid];
    const float sg = (tid & 1) ? -1.f : 1.f;
    dxv = L * cs;
    dyv = L * sn * sg;
  }
  float ix = dxv, iy = dyv;
#pragma unroll
  for (int off = 1; off < 64; off <<= 1) {
    float wx = shflu(ix, off);
    float wy = shflu(iy, off);
    if (lane >= off) { ix += wx; iy += wy; }
  }
  if (lane == 63) { s_ws2[wave][0] = ix; s_ws2[wave][1] = iy; }
  __syncthreads();  // (2)
  float px = 0.f, py = 0.f;
  for (int j = 0; j < wave; ++j) { px += s_ws2[j][0]; py += s_ws2[j][1]; }
  float fx = ix + px, fy = iy + py;
  float cxe = shflu(fx, 1), cye = shflu(fy, 1);
  if (lane == 0) { cxe = px; cye = py; }
  s_cx[tid] = cxe;
  s_cy[tid] = cye;
  __syncthreads();  // (3)

  // ---------- Phase B: per-side quaternion prefix product ----------
  // left (side 0): bonds b_k = cart[255-k]-cart[256-k], k=0..255; phi_k = dih[254-k]+pi, k<255
  // right (side 1): bonds b_k = cart[257+k]-cart[256+k], k=0..254; phi_k = dih[255+k]+pi, k<254
  const int side = tid >> 8;
  const int k = tid & 255;
  const int swave = (tid >> 6) & 3;
  const int nb = side ? 255 : 256;
  const int ng = side ? 254 : 255;

  float bx = 0.f, by = 0.f;
  if (k < nb) {
    const int i0 = side ? (256 + k) : (256 - k);
    const int i1 = side ? (257 + k) : (255 - k);
    bx = s_cx[i1] - s_cx[i0];
    by = s_cy[i1] - s_cy[i0];
  }

  // G_k as quaternion (identity when k >= ng)
  float qw = 1.f, qx = 0.f, qy = 0.f, qz = 0.f;
  if (k < ng) {
    const float phi = side ? (dih[(size_t)b * kNDih + 255 + k] + kPi)
                           : (dih[(size_t)b * kNDih + 254 - k] + kPi);
    const float rn = rsqrtf(bx * bx + by * by);
    float sh, ch;
    sincosf(0.5f * phi, &sh, &ch);
    qw = ch;
    qx = sh * bx * rn;
    qy = sh * by * rn;
    // qz = 0 (planar axis)
  }
  // intra-wave non-commutative inclusive scan: q_l <- q_{l-off} (x) q_l
#pragma unroll
  for (int off = 1; off < 64; off <<= 1) {
    float aw = shflu(qw, off), ax = shflu(qx, off),
          ay = shflu(qy, off), az = shflu(qz, off);
    if (lane >= off) {
      const float nw = aw * qw - ax * qx - ay * qy - az * qz;
      const float nx = aw * qx + ax * qw + ay * qz - az * qy;
      const float ny = aw * qy - ax * qz + ay * qw + az * qx;
      const float nz = aw * qz + ax * qy - ay * qx + az * qw;
      qw = nw; qx = nx; qy = ny; qz = nz;
    }
  }
  if (lane == 63) {
    float* W = s_wq[side][swave];
    W[0] = qw; W[1] = qx; W[2] = qy; W[3] = qz;
  }
  __syncthreads();  // (4)
  // wave prefix P = product of earlier wave totals (in order)
  float Pw = 1.f, Px = 0.f, Py = 0.f, Pz = 0.f;
  for (int j = 0; j < swave; ++j) {
    const float* W = s_wq[side][j];
    const float aw = Pw, ax = Px, ay = Py, az = Pz;
    const float bw = W[0], bxq = W[1], byq = W[2], bzq = W[3];
    Pw = aw * bw - ax * bxq - ay * byq - az * bzq;
    Px = aw * bxq + ax * bw + ay * bzq - az * byq;
    Py = aw * byq - ax * bzq + ay * bw + az * bxq;
    Pz = aw * bzq + ax * byq - ay * bxq + az * bw;
  }
  // full inclusive Q = P (x) q
  float Qw = Pw * qw - Px * qx - Py * qy - Pz * qz;
  float Qx = Pw * qx + Px * qw + Py * qz - Pz * qy;
  float Qy = Pw * qy - Px * qz + Py * qw + Pz * qx;
  float Qz = Pw * qz + Px * qy - Py * qx + Pz * qw;
  // exclusive W_k = Q_{k-1}
  float Ww = shflu(Qw, 1), Wx = shflu(Qx, 1), Wy = shflu(Qy, 1), Wz = shflu(Qz, 1);
  if (lane == 0) { Ww = Pw; Wx = Px; Wy = Py; Wz = Pz; }

  // rotate bond (bx,by,0) by quaternion W: c = b + Ww*t + Wv x t, t = 2 Wv x b
  const float tx = -2.f * Wz * by;
  const float ty = 2.f * Wz * bx;
  const float tz = 2.f * (Wx * by - Wy * bx);
  float cx = bx + Ww * tx + (Wy * tz - Wz * ty);
  float cy = by + Ww * ty + (Wz * tx - Wx * tz);
  float cz = Ww * tz + (Wx * ty - Wy * tx);

  // ---------- Phase B2: float3 inclusive scan of rotated bonds ----------
  float vx = cx, vy = cy, vz = cz;
#pragma unroll
  for (int off = 1; off < 64; off <<= 1) {
    float ax = shflu(vx, off), ay = shflu(vy, off), az = shflu(vz, off);
    if (lane >= off) { vx += ax; vy += ay; vz += az; }
  }
  if (lane == 63) {
    float* V = s_wv[side][swave];
    V[0] = vx; V[1] = vy; V[2] = vz;
  }
  __syncthreads();  // (5)
  float sx = 0.f, sy = 0.f, sz = 0.f;
  for (int j = 0; j < swave; ++j) {
    const float* V = s_wv[side][j];
    sx += V[0]; sy += V[1]; sz += V[2];
  }
  vx += sx; vy += sy; vz += sz;

  // ---------- output assembly: flip(new_l) ++ new_r[3:] ----------
  const float bpx = s_cx[256], bpy = s_cy[256];
  const float ox = bpx + vx, oy = bpy + vy, oz = vz;
  float* outb = out + (size_t)b * 512 * 3;
  if (side == 0) {
    const int row = 255 - k;
    outb[row * 3 + 0] = ox; outb[row * 3 + 1] = oy; outb[row * 3 + 2] = oz;
  } else {
    if (k >= 1 && k <= 254) {
      const int row = 257 + k;
      outb[row * 3 + 0] = ox; outb[row * 3 + 1] = oy; outb[row * 3 + 2] = oz;
    }
    if (k == 0) {
      outb[256 * 3 + 0] = bpx; outb[256 * 3 + 1] = bpy; outb[256 * 3 + 2] = 0.f;
    }
    if (k == 255) {
      outb[257 * 3 + 0] = s_cx[257]; outb[257 * 3 + 1] = s_cy[257];
      outb[257 * 3 + 2] = 0.f;
    }
  }
}

extern "C" void kernel_launch(void* const* d_in, const int* in_sizes, int n_in,
                              void* d_out, int out_size, void* d_ws, size_t ws_size,
                              hipStream_t stream) {
  const float* distances = (const float*)d_in[0];
  const float* angles    = (const float*)d_in[1];
  const float* dihedrals = (const float*)d_in[2];
  float* lengths = (float*)d_ws;  // 511 floats of scratch, written then read
  float* out = (float*)d_out;
  k_lengths<<<kNDist, 256, 0, stream>>>(distances, lengths);
  k_backmap<<<kB, 512, 0, stream>>>(angles, dihedrals, lengths, out);
}